// Round 2
// baseline (1468.801 us; speedup 1.0000x reference)
//
#include <hip/hip_runtime.h>
#include <hip/hip_bf16.h>

#define NN 500000
#define EE 2000000
#define GG 16384
#define ND 44
#define ED 12
#define HH 64
#define EMB 128
#define NBLK 123          // ceil(NN / 4096) scan blocks

typedef __attribute__((ext_vector_type(8))) short bf16x8;
typedef __attribute__((ext_vector_type(4))) float f32x4;

// fp32 -> bf16 round-to-nearest-even, bit pattern as short
__device__ inline short f2bf(float v) {
    unsigned int x = __builtin_bit_cast(unsigned int, v);
    x += 0x7FFFu + ((x >> 16) & 1u);
    return (short)(x >> 16);
}

// ---------------------------------------------------------------------------
// Weight prep: transpose to [n][k] layout, cast to bf16, zero-pad K of w1a to 64
// Layout in `o` (shorts): w1a_t[64][64] | w1b_t[64][64] | w2a_t[128][64] | w2b_t[128][128]
__global__ __launch_bounds__(256) void prep_weights(
    const float* __restrict__ w1a, const float* __restrict__ w1b,
    const float* __restrict__ w2a, const float* __restrict__ w2b,
    short* __restrict__ o) {
    int t = blockIdx.x * 256 + threadIdx.x;
    if (t < 4096) {
        int n = t >> 6, k = t & 63;
        o[t] = f2bf(k < ND ? w1a[k * HH + n] : 0.f);
    } else if (t < 8192) {
        int u = t - 4096; int n = u >> 6, k = u & 63;
        o[t] = f2bf(w1b[k * HH + n]);
    } else if (t < 16384) {
        int u = t - 8192; int n = u >> 6, k = u & 63;
        o[t] = f2bf(w2a[k * EMB + n]);
    } else if (t < 32768) {
        int u = t - 16384; int n = u >> 7, k = u & 127;
        o[t] = f2bf(w2b[k * EMB + n]);
    }
}

// ---------------------------------------------------------------------------
// CSR build: histogram of dst, exclusive scan, scatter (src, eid) by dst.
__global__ __launch_bounds__(256) void hist_kernel(const int* __restrict__ ei,
                                                   int* __restrict__ deg) {
    int e = blockIdx.x * 256 + threadIdx.x;
    if (e < EE) atomicAdd(&deg[ei[EE + e]], 1);
}

__global__ __launch_bounds__(256) void scan_reduce(const int* __restrict__ deg,
                                                   int* __restrict__ bsum) {
    int b = blockIdx.x, t = threadIdx.x;
    int base = b * 4096;
    int s = 0;
    for (int i = t; i < 4096; i += 256) {
        int g = base + i;
        if (g < NN) s += deg[g];
    }
#pragma unroll
    for (int off = 32; off; off >>= 1) s += __shfl_xor(s, off);
    __shared__ int ws[4];
    if ((t & 63) == 0) ws[t >> 6] = s;
    __syncthreads();
    if (t == 0) bsum[b] = ws[0] + ws[1] + ws[2] + ws[3];
}

__global__ __launch_bounds__(128) void scan_mid(const int* __restrict__ bsum,
                                                int* __restrict__ boff,
                                                int* __restrict__ rowptr) {
    int t = threadIdx.x;  // 128 threads, 2 waves
    int v = (t < NBLK) ? bsum[t] : 0;
    int x = v;
#pragma unroll
    for (int off = 1; off < 64; off <<= 1) {
        int y = __shfl_up(x, off);
        if ((t & 63) >= off) x += y;
    }
    __shared__ int wt[2];
    if ((t & 63) == 63) wt[t >> 6] = x;
    __syncthreads();
    int xx = x + ((t >= 64) ? wt[0] : 0);
    if (t < NBLK) boff[t] = xx - v;      // exclusive
    if (t == 127) rowptr[NN] = xx;       // total == EE
}

__global__ __launch_bounds__(256) void scan_final(const int* __restrict__ deg,
                                                  const int* __restrict__ boff,
                                                  int* __restrict__ rowptr,
                                                  int* __restrict__ cursor) {
    int b = blockIdx.x, t = threadIdx.x;
    int base = b * 4096 + t * 16;
    int loc[16];
    int s = 0;
#pragma unroll
    for (int j = 0; j < 16; ++j) {
        int g = base + j;
        loc[j] = (g < NN) ? deg[g] : 0;
        s += loc[j];
    }
    int xinc = s;
#pragma unroll
    for (int off = 1; off < 64; off <<= 1) {
        int y = __shfl_up(xinc, off);
        if ((t & 63) >= off) xinc += y;
    }
    __shared__ int wt[4];
    if ((t & 63) == 63) wt[t >> 6] = xinc;
    __syncthreads();
    int wv = t >> 6, woff = 0;
#pragma unroll
    for (int k = 0; k < 4; ++k)
        if (k < wv) woff += wt[k];
    int run = boff[b] + woff + (xinc - s);
#pragma unroll
    for (int j = 0; j < 16; ++j) {
        int g = base + j;
        if (g < NN) { rowptr[g] = run; cursor[g] = run; }
        run += loc[j];
    }
}

__global__ __launch_bounds__(256) void scatter_kernel(const int* __restrict__ ei,
                                                      int* __restrict__ cursor,
                                                      int2* __restrict__ csr) {
    int e = blockIdx.x * 256 + threadIdx.x;
    if (e < EE) {
        int dst = ei[EE + e];
        int pos = atomicAdd(&cursor[dst], 1);
        csr[pos] = make_int2(ei[e], e);
    }
}

// ---------------------------------------------------------------------------
// Gather aggregation layer 1: xin[i] = x[i] + sum_{e: dst=i} relu(x[src] + ea@W + b)
// One wave per node; lane d owns dim d; 2-deep software pipeline on the gathers.
__global__ __launch_bounds__(256) void agg1(
    const float* __restrict__ x, const float* __restrict__ ea,
    const float* __restrict__ ew, const float* __restrict__ eb,
    const int* __restrict__ rowptr, const int2* __restrict__ csr,
    float* __restrict__ xin) {
    int d = threadIdx.x & 63;
    int wv = threadIdx.x >> 6;
    int i = __builtin_amdgcn_readfirstlane(blockIdx.x * 4 + wv);
    if (i >= NN) return;
    float wreg[ED];
#pragma unroll
    for (int k = 0; k < ED; ++k) wreg[k] = (d < ND) ? ew[k * ND + d] : 0.f;
    float breg = (d < ND) ? eb[d] : 0.f;
    int beg = rowptr[i], end = rowptr[i + 1];
    float acc = 0.f;
    int2 se0 = make_int2(0, 0);
    float ev0 = 0.f, xv0 = 0.f;
    if (beg < end) {
        se0 = csr[beg];
        ev0 = (d < ED) ? ea[se0.y * ED + d] : 0.f;
        xv0 = (d < ND) ? x[se0.x * ND + d] : 0.f;
    }
    for (int p = beg; p < end; ++p) {
        int2 se1 = se0;
        float ev1 = 0.f, xv1 = 0.f;
        if (p + 1 < end) {
            se1 = csr[p + 1];
            ev1 = (d < ED) ? ea[se1.y * ED + d] : 0.f;
            xv1 = (d < ND) ? x[se1.x * ND + d] : 0.f;
        }
        float elin = breg;
#pragma unroll
        for (int k = 0; k < ED; ++k) elin = fmaf(__shfl(ev0, k), wreg[k], elin);
        acc += fmaxf(xv0 + elin, 0.f);
        se0 = se1; ev0 = ev1; xv0 = xv1;
    }
    if (d < ND) xin[i * ND + d] = acc + x[i * ND + d];
}

// Gather aggregation layer 2: hin2[i] = h[i] + sum relu(h[src] + ea@W2 + b2), 64 dims
__global__ __launch_bounds__(256) void agg2(
    const float* __restrict__ h, const float* __restrict__ ea,
    const float* __restrict__ ew, const float* __restrict__ eb,
    const int* __restrict__ rowptr, const int2* __restrict__ csr,
    float* __restrict__ hin2) {
    int d = threadIdx.x & 63;
    int wv = threadIdx.x >> 6;
    int i = __builtin_amdgcn_readfirstlane(blockIdx.x * 4 + wv);
    if (i >= NN) return;
    float wreg[ED];
#pragma unroll
    for (int k = 0; k < ED; ++k) wreg[k] = ew[k * HH + d];
    float breg = eb[d];
    int beg = rowptr[i], end = rowptr[i + 1];
    float acc = 0.f;
    int2 se0 = make_int2(0, 0);
    float ev0 = 0.f, hv0 = 0.f;
    if (beg < end) {
        se0 = csr[beg];
        ev0 = (d < ED) ? ea[se0.y * ED + d] : 0.f;
        hv0 = h[se0.x * HH + d];
    }
    for (int p = beg; p < end; ++p) {
        int2 se1 = se0;
        float ev1 = 0.f, hv1 = 0.f;
        if (p + 1 < end) {
            se1 = csr[p + 1];
            ev1 = (d < ED) ? ea[se1.y * ED + d] : 0.f;
            hv1 = h[se1.x * HH + d];
        }
        float elin = breg;
#pragma unroll
        for (int k = 0; k < ED; ++k) elin = fmaf(__shfl(ev0, k), wreg[k], elin);
        acc += fmaxf(hv0 + elin, 0.f);
        se0 = se1; ev0 = ev1; hv0 = hv1;
    }
    hin2[i * HH + d] = acc + h[i * HH + d];
}

// ---------------------------------------------------------------------------
// Node MLP 1: h = relu( relu(xin @ w1a + b1a) @ w1b + b1b ), 44(->64 pad)->64->64
#define HSTR1 68
__global__ __launch_bounds__(256) void mlp1(
    const float* __restrict__ xin,
    const short* __restrict__ w1a_t, const float* __restrict__ b1a,
    const short* __restrict__ w1b_t, const float* __restrict__ b1b,
    float* __restrict__ h) {
    __shared__ float hid[4][16 * HSTR1];
    int lane = threadIdx.x & 63;
    int wv = threadIdx.x >> 6;
    int tile = blockIdx.x * 4 + wv;
    bool act = tile < (NN / 16);
    int tile_c = act ? tile : (NN / 16 - 1);
    int node0 = tile_c * 16;
    int mrow = lane & 15, q = lane >> 4;
    int m = node0 + mrow;
    float* hw = hid[wv];

    bf16x8 afrag[2];
    {   // s=0: k = q*8 .. q*8+7, all < 32 < 44 -> vector loads (rows 176B, 16B-aligned)
        f32x4 v0 = *(const f32x4*)(xin + m * ND + q * 8);
        f32x4 v1 = *(const f32x4*)(xin + m * ND + q * 8 + 4);
#pragma unroll
        for (int j = 0; j < 4; ++j) { afrag[0][j] = f2bf(v0[j]); afrag[0][j + 4] = f2bf(v1[j]); }
    }
#pragma unroll
    for (int j = 0; j < 8; ++j) {   // s=1: k = 32 + q*8 + j, pad past 44
        int k = 32 + q * 8 + j;
        afrag[1][j] = f2bf(k < ND ? xin[m * ND + k] : 0.f);
    }
#pragma unroll
    for (int nt = 0; nt < 4; ++nt) {
        int n = nt * 16 + mrow;
        float bias = b1a[n];
        f32x4 acc = {bias, bias, bias, bias};
#pragma unroll
        for (int s = 0; s < 2; ++s) {
            bf16x8 bfrag = *(const bf16x8*)(w1a_t + n * 64 + s * 32 + q * 8);
            acc = __builtin_amdgcn_mfma_f32_16x16x32_bf16(afrag[s], bfrag, acc, 0, 0, 0);
        }
#pragma unroll
        for (int r = 0; r < 4; ++r)
            hw[(q * 4 + r) * HSTR1 + n] = fmaxf(acc[r], 0.f);
    }
    __syncthreads();
    bf16x8 af2[2];
#pragma unroll
    for (int s = 0; s < 2; ++s) {
        f32x4 v0 = *(const f32x4*)(hw + mrow * HSTR1 + s * 32 + q * 8);
        f32x4 v1 = *(const f32x4*)(hw + mrow * HSTR1 + s * 32 + q * 8 + 4);
#pragma unroll
        for (int j = 0; j < 4; ++j) { af2[s][j] = f2bf(v0[j]); af2[s][j + 4] = f2bf(v1[j]); }
    }
#pragma unroll
    for (int nt = 0; nt < 4; ++nt) {
        int n = nt * 16 + mrow;
        float bias = b1b[n];
        f32x4 acc = {bias, bias, bias, bias};
#pragma unroll
        for (int s = 0; s < 2; ++s) {
            bf16x8 bfrag = *(const bf16x8*)(w1b_t + n * 64 + s * 32 + q * 8);
            acc = __builtin_amdgcn_mfma_f32_16x16x32_bf16(af2[s], bfrag, acc, 0, 0, 0);
        }
        if (act) {
#pragma unroll
            for (int r = 0; r < 4; ++r)
                h[(node0 + q * 4 + r) * HH + n] = fmaxf(acc[r], 0.f);
        }
    }
}

// ---------------------------------------------------------------------------
// Node MLP 2 + fused mean-pool accumulate: out = relu(hin2 @ w2a + b2a) @ w2b + b2b
#define HSTR2 132
__global__ __launch_bounds__(256) void mlp2(
    const float* __restrict__ hin2,
    const short* __restrict__ w2a_t, const float* __restrict__ b2a,
    const short* __restrict__ w2b_t, const float* __restrict__ b2b,
    const int* __restrict__ batch, float* __restrict__ sums) {
    __shared__ float buf[4][16 * HSTR2];
    int lane = threadIdx.x & 63;
    int wv = threadIdx.x >> 6;
    int tile = blockIdx.x * 4 + wv;
    bool act = tile < (NN / 16);
    int tile_c = act ? tile : (NN / 16 - 1);
    int node0 = tile_c * 16;
    int mrow = lane & 15, q = lane >> 4;
    int m = node0 + mrow;
    float* bw = buf[wv];

    bf16x8 afrag[2];
#pragma unroll
    for (int s = 0; s < 2; ++s) {
        f32x4 h0 = *(const f32x4*)(hin2 + m * HH + s * 32 + q * 8);
        f32x4 h1 = *(const f32x4*)(hin2 + m * HH + s * 32 + q * 8 + 4);
#pragma unroll
        for (int j = 0; j < 4; ++j) {
            afrag[s][j] = f2bf(h0[j]);
            afrag[s][j + 4] = f2bf(h1[j]);
        }
    }
#pragma unroll
    for (int nt = 0; nt < 8; ++nt) {
        int n = nt * 16 + mrow;
        float bias = b2a[n];
        f32x4 acc = {bias, bias, bias, bias};
#pragma unroll
        for (int s = 0; s < 2; ++s) {
            bf16x8 bfrag = *(const bf16x8*)(w2a_t + n * HH + s * 32 + q * 8);
            acc = __builtin_amdgcn_mfma_f32_16x16x32_bf16(afrag[s], bfrag, acc, 0, 0, 0);
        }
#pragma unroll
        for (int r = 0; r < 4; ++r)
            bw[(q * 4 + r) * HSTR2 + n] = fmaxf(acc[r], 0.f);
    }
    __syncthreads();
    bf16x8 af2[4];
#pragma unroll
    for (int s = 0; s < 4; ++s) {
        f32x4 v0 = *(const f32x4*)(bw + mrow * HSTR2 + s * 32 + q * 8);
        f32x4 v1 = *(const f32x4*)(bw + mrow * HSTR2 + s * 32 + q * 8 + 4);
#pragma unroll
        for (int j = 0; j < 4; ++j) { af2[s][j] = f2bf(v0[j]); af2[s][j + 4] = f2bf(v1[j]); }
    }
    __syncthreads();
    f32x4 oacc[8];
#pragma unroll
    for (int nt = 0; nt < 8; ++nt) {
        int n = nt * 16 + mrow;
        float bias = b2b[n];
        f32x4 acc = {bias, bias, bias, bias};
#pragma unroll
        for (int s = 0; s < 4; ++s) {
            bf16x8 bfrag = *(const bf16x8*)(w2b_t + n * EMB + s * 32 + q * 8);
            acc = __builtin_amdgcn_mfma_f32_16x16x32_bf16(af2[s], bfrag, acc, 0, 0, 0);
        }
        oacc[nt] = acc;
    }
#pragma unroll
    for (int nt = 0; nt < 8; ++nt)
#pragma unroll
        for (int r = 0; r < 4; ++r)
            bw[(q * 4 + r) * HSTR2 + nt * 16 + mrow] = oacc[nt][r];
    __syncthreads();
    int bv = (act && lane < 16) ? batch[node0 + lane] : 0;
    if (act) {
#pragma unroll
        for (int cp = 0; cp < 2; ++cp) {
            int col = lane + cp * 64;
            float run = 0.f;
            int bprev = __shfl(bv, 0);
            for (int i = 0; i < 16; ++i) {
                int bg = __shfl(bv, i);
                if (bg != bprev) {
                    atomicAdd(&sums[bprev * EMB + col], run);
                    run = 0.f; bprev = bg;
                }
                run += bw[i * HSTR2 + col];
            }
            atomicAdd(&sums[bprev * EMB + col], run);
        }
    }
}

// ---------------------------------------------------------------------------
__global__ __launch_bounds__(128) void finalize(
    const float* __restrict__ sums, const int* __restrict__ batch,
    float* __restrict__ out) {
    int g = blockIdx.x;
    __shared__ int cnt_s;
    if (threadIdx.x == 0) {
        int lo = 0, hi = NN;
        while (lo < hi) { int mid = (lo + hi) >> 1; if (batch[mid] < g) lo = mid + 1; else hi = mid; }
        int lo2 = lo, hi2 = NN;
        while (lo2 < hi2) { int mid = (lo2 + hi2) >> 1; if (batch[mid] < g + 1) lo2 = mid + 1; else hi2 = mid; }
        cnt_s = lo2 - lo;
    }
    __syncthreads();
    int c = cnt_s > 1 ? cnt_s : 1;
    out[g * EMB + threadIdx.x] = sums[g * EMB + threadIdx.x] / (float)c;
}

// ---------------------------------------------------------------------------
extern "C" void kernel_launch(void* const* d_in, const int* in_sizes, int n_in,
                              void* d_out, int out_size, void* d_ws, size_t ws_size,
                              hipStream_t stream) {
    const float* x    = (const float*)d_in[0];
    const float* ea   = (const float*)d_in[1];
    const int*   ei   = (const int*)d_in[2];
    const int*   batch= (const int*)d_in[3];
    const float* el1w = (const float*)d_in[4];
    const float* el1b = (const float*)d_in[5];
    const float* w1a  = (const float*)d_in[6];
    const float* b1a  = (const float*)d_in[7];
    const float* w1b  = (const float*)d_in[8];
    const float* b1b  = (const float*)d_in[9];
    const float* el2w = (const float*)d_in[10];
    const float* el2b = (const float*)d_in[11];
    const float* w2a  = (const float*)d_in[12];
    const float* b2a  = (const float*)d_in[13];
    const float* w2b  = (const float*)d_in[14];
    const float* b2b  = (const float*)d_in[15];

    char* ws = (char*)d_ws;
    // Region A: xin [N][44] f32 (88 MB) during layer 1, reused as hin2 [N][64] (128 MB)
    float* xin   = (float*)ws;
    float* hin2  = (float*)ws;
    float* hbuf  = (float*)(ws + 128000000);                    // [N][64] f32
    int2*  csr   = (int2*)(ws + 256000000);                     // [E] (src, eid)
    int*   rowptr= (int*)(ws + 272000000);                      // N+1
    int*   cursor= (int*)(ws + 274000064);                      // N
    int*   deg   = (int*)(ws + 276000064);                      // N
    int*   bsum  = (int*)(ws + 278000064);                      // NBLK
    int*   boff  = (int*)(ws + 278000576);                      // NBLK
    float* sums  = (float*)(ws + 278001088);                    // G*128 f32
    short* wts   = (short*)(ws + 286389696);                    // 32768 shorts
    short* w1a_t = wts;
    short* w1b_t = wts + 4096;
    short* w2a_t = wts + 8192;
    short* w2b_t = wts + 16384;

    hipMemsetAsync(deg, 0, (size_t)NN * 4, stream);
    hipMemsetAsync(sums, 0, (size_t)GG * EMB * 4, stream);

    prep_weights<<<128, 256, 0, stream>>>(w1a, w1b, w2a, w2b, wts);
    // CSR build
    hist_kernel<<<(EE + 255) / 256, 256, 0, stream>>>(ei, deg);
    scan_reduce<<<NBLK, 256, 0, stream>>>(deg, bsum);
    scan_mid<<<1, 128, 0, stream>>>(bsum, boff, rowptr);
    scan_final<<<NBLK, 256, 0, stream>>>(deg, boff, rowptr, cursor);
    scatter_kernel<<<(EE + 255) / 256, 256, 0, stream>>>(ei, cursor, csr);
    // Layer 1
    agg1<<<NN / 4, 256, 0, stream>>>(x, ea, el1w, el1b, rowptr, csr, xin);
    mlp1<<<7813, 256, 0, stream>>>(xin, w1a_t, b1a, w1b_t, b1b, hbuf);
    // Layer 2
    agg2<<<NN / 4, 256, 0, stream>>>(hbuf, ea, el2w, el2b, rowptr, csr, hin2);
    mlp2<<<7813, 256, 0, stream>>>(hin2, w2a_t, b2a, w2b_t, b2b, batch, sums);
    finalize<<<GG, 128, 0, stream>>>(sums, batch, (float*)d_out);
}

// Round 3
// 1436.829 us; speedup vs baseline: 1.0223x; 1.0223x over previous
//
#include <hip/hip_runtime.h>
#include <hip/hip_bf16.h>

#define NN 500000
#define EE 2000000
#define GG 16384
#define ND 44
#define ED 12
#define HH 64
#define EMB 128
#define NBLK 123          // ceil(NN / 4096) scan blocks

typedef __attribute__((ext_vector_type(8))) short bf16x8;
typedef __attribute__((ext_vector_type(4))) float f32x4;

// fp32 -> bf16 round-to-nearest-even, bit pattern as short
__device__ inline short f2bf(float v) {
    unsigned int x = __builtin_bit_cast(unsigned int, v);
    x += 0x7FFFu + ((x >> 16) & 1u);
    return (short)(x >> 16);
}

// ---------------------------------------------------------------------------
// Weight prep: transpose to [n][k] layout, cast to bf16, zero-pad K of w1a to 64
__global__ __launch_bounds__(256) void prep_weights(
    const float* __restrict__ w1a, const float* __restrict__ w1b,
    const float* __restrict__ w2a, const float* __restrict__ w2b,
    short* __restrict__ o) {
    int t = blockIdx.x * 256 + threadIdx.x;
    if (t < 4096) {
        int n = t >> 6, k = t & 63;
        o[t] = f2bf(k < ND ? w1a[k * HH + n] : 0.f);
    } else if (t < 8192) {
        int u = t - 4096; int n = u >> 6, k = u & 63;
        o[t] = f2bf(w1b[k * HH + n]);
    } else if (t < 16384) {
        int u = t - 8192; int n = u >> 6, k = u & 63;
        o[t] = f2bf(w2a[k * EMB + n]);
    } else if (t < 32768) {
        int u = t - 16384; int n = u >> 7, k = u & 127;
        o[t] = f2bf(w2b[k * EMB + n]);
    }
}

// ---------------------------------------------------------------------------
// CSR build: histogram of dst, exclusive scan, scatter (src, eid) by dst.
__global__ __launch_bounds__(256) void hist_kernel(const int* __restrict__ ei,
                                                   int* __restrict__ deg) {
    int e = blockIdx.x * 256 + threadIdx.x;
    if (e < EE) atomicAdd(&deg[ei[EE + e]], 1);
}

__global__ __launch_bounds__(256) void scan_reduce(const int* __restrict__ deg,
                                                   int* __restrict__ bsum) {
    int b = blockIdx.x, t = threadIdx.x;
    int base = b * 4096;
    int s = 0;
    for (int i = t; i < 4096; i += 256) {
        int g = base + i;
        if (g < NN) s += deg[g];
    }
#pragma unroll
    for (int off = 32; off; off >>= 1) s += __shfl_xor(s, off);
    __shared__ int ws[4];
    if ((t & 63) == 0) ws[t >> 6] = s;
    __syncthreads();
    if (t == 0) bsum[b] = ws[0] + ws[1] + ws[2] + ws[3];
}

__global__ __launch_bounds__(128) void scan_mid(const int* __restrict__ bsum,
                                                int* __restrict__ boff,
                                                int* __restrict__ rowptr) {
    int t = threadIdx.x;
    int v = (t < NBLK) ? bsum[t] : 0;
    int x = v;
#pragma unroll
    for (int off = 1; off < 64; off <<= 1) {
        int y = __shfl_up(x, off);
        if ((t & 63) >= off) x += y;
    }
    __shared__ int wt[2];
    if ((t & 63) == 63) wt[t >> 6] = x;
    __syncthreads();
    int xx = x + ((t >= 64) ? wt[0] : 0);
    if (t < NBLK) boff[t] = xx - v;
    if (t == 127) rowptr[NN] = xx;
}

__global__ __launch_bounds__(256) void scan_final(const int* __restrict__ deg,
                                                  const int* __restrict__ boff,
                                                  int* __restrict__ rowptr,
                                                  int* __restrict__ cursor) {
    int b = blockIdx.x, t = threadIdx.x;
    int base = b * 4096 + t * 16;
    int loc[16];
    int s = 0;
#pragma unroll
    for (int j = 0; j < 16; ++j) {
        int g = base + j;
        loc[j] = (g < NN) ? deg[g] : 0;
        s += loc[j];
    }
    int xinc = s;
#pragma unroll
    for (int off = 1; off < 64; off <<= 1) {
        int y = __shfl_up(xinc, off);
        if ((t & 63) >= off) xinc += y;
    }
    __shared__ int wt[4];
    if ((t & 63) == 63) wt[t >> 6] = xinc;
    __syncthreads();
    int wv = t >> 6, woff = 0;
#pragma unroll
    for (int k = 0; k < 4; ++k)
        if (k < wv) woff += wt[k];
    int run = boff[b] + woff + (xinc - s);
#pragma unroll
    for (int j = 0; j < 16; ++j) {
        int g = base + j;
        if (g < NN) { rowptr[g] = run; cursor[g] = run; }
        run += loc[j];
    }
}

__global__ __launch_bounds__(256) void scatter_kernel(const int* __restrict__ ei,
                                                      int* __restrict__ cursor,
                                                      int2* __restrict__ csr) {
    int e = blockIdx.x * 256 + threadIdx.x;
    if (e < EE) {
        int dst = ei[EE + e];
        int pos = atomicAdd(&cursor[dst], 1);
        csr[pos] = make_int2(ei[e], e);
    }
}

// ---------------------------------------------------------------------------
// Gather aggregation, 8 nodes per wave, lane-parallel CSR preload, 4-deep
// data prefetch. out[i] = x[i] + sum_{e: dst=i} relu(x[src] + ea@W + b).
// D = node feature dim (44 or 64); lane d owns dim d; every node row is
// written exactly once (no atomics, no memset needed).
template <int D>
__global__ __launch_bounds__(256) void agg_gather(
    const float* __restrict__ xf, const float* __restrict__ ea,
    const float* __restrict__ ew, const float* __restrict__ eb,
    const int* __restrict__ rowptr, const int2* __restrict__ csr,
    float* __restrict__ out) {
    int lane = threadIdx.x & 63;
    int wv = threadIdx.x >> 6;
    int i0 = (blockIdx.x * 4 + wv) * 8;   // first of this wave's 8 nodes
    if (i0 >= NN) return;
    float wreg[ED];
#pragma unroll
    for (int k = 0; k < ED; ++k) wreg[k] = (lane < D) ? ew[k * D + lane] : 0.f;
    float breg = (lane < D) ? eb[lane] : 0.f;
    int rp = (lane <= 8) ? rowptr[i0 + lane] : 0;   // 9 boundaries, lane-held
    int beg = __shfl(rp, 0);
    int end = __shfl(rp, 8);
    float acc = 0.f;
    int np = 0;                                      // node offset in [0,8)
    // flush leading empty nodes (boundary == beg)
    while (np < 8 && __shfl(rp, np + 1) == beg) {
        if (lane < D) out[(i0 + np) * D + lane] = xf[(i0 + np) * D + lane];
        ++np;
    }
    for (int cs = beg; cs < end; cs += 64) {
        int cnt = min(64, end - cs);
        int2 myse = make_int2(0, 0);
        if (lane < cnt) myse = csr[cs + lane];       // coalesced span preload
        float ev[4], xv[4];
#pragma unroll
        for (int s = 0; s < 4; ++s) {
            ev[s] = 0.f; xv[s] = 0.f;
            if (s < cnt) {
                int src = __shfl(myse.x, s);
                int eid = __shfl(myse.y, s);
                if (lane < ED) ev[s] = ea[eid * ED + lane];
                if (lane < D)  xv[s] = xf[src * D + lane];
            }
        }
        for (int j = 0; j < cnt; ++j) {
            int s = j & 3;
            float elin = breg;
#pragma unroll
            for (int k = 0; k < ED; ++k) elin = fmaf(__shfl(ev[s], k), wreg[k], elin);
            acc += fmaxf(xv[s] + elin, 0.f);
            int jn = j + 4;
            if (jn < cnt) {                          // refill slot s for j+4
                int src = __shfl(myse.x, jn);
                int eid = __shfl(myse.y, jn);
                ev[s] = (lane < ED) ? ea[eid * ED + lane] : 0.f;
                xv[s] = (lane < D)  ? xf[src * D + lane] : 0.f;
            }
            int p1 = cs + j + 1;
            while (np < 8 && __shfl(rp, np + 1) == p1) {   // node(s) finished
                if (lane < D) out[(i0 + np) * D + lane] = acc + xf[(i0 + np) * D + lane];
                acc = 0.f;
                ++np;
            }
        }
    }
}

// ---------------------------------------------------------------------------
// Node MLP 1: h = relu( relu(xin @ w1a + b1a) @ w1b + b1b ), 44(->64 pad)->64->64
#define HSTR1 68
__global__ __launch_bounds__(256) void mlp1(
    const float* __restrict__ xin,
    const short* __restrict__ w1a_t, const float* __restrict__ b1a,
    const short* __restrict__ w1b_t, const float* __restrict__ b1b,
    float* __restrict__ h) {
    __shared__ float hid[4][16 * HSTR1];
    int lane = threadIdx.x & 63;
    int wv = threadIdx.x >> 6;
    int tile = blockIdx.x * 4 + wv;
    bool act = tile < (NN / 16);
    int tile_c = act ? tile : (NN / 16 - 1);
    int node0 = tile_c * 16;
    int mrow = lane & 15, q = lane >> 4;
    int m = node0 + mrow;
    float* hw = hid[wv];

    bf16x8 afrag[2];
    {
        f32x4 v0 = *(const f32x4*)(xin + m * ND + q * 8);
        f32x4 v1 = *(const f32x4*)(xin + m * ND + q * 8 + 4);
#pragma unroll
        for (int j = 0; j < 4; ++j) { afrag[0][j] = f2bf(v0[j]); afrag[0][j + 4] = f2bf(v1[j]); }
    }
#pragma unroll
    for (int j = 0; j < 8; ++j) {
        int k = 32 + q * 8 + j;
        afrag[1][j] = f2bf(k < ND ? xin[m * ND + k] : 0.f);
    }
#pragma unroll
    for (int nt = 0; nt < 4; ++nt) {
        int n = nt * 16 + mrow;
        float bias = b1a[n];
        f32x4 acc = {bias, bias, bias, bias};
#pragma unroll
        for (int s = 0; s < 2; ++s) {
            bf16x8 bfrag = *(const bf16x8*)(w1a_t + n * 64 + s * 32 + q * 8);
            acc = __builtin_amdgcn_mfma_f32_16x16x32_bf16(afrag[s], bfrag, acc, 0, 0, 0);
        }
#pragma unroll
        for (int r = 0; r < 4; ++r)
            hw[(q * 4 + r) * HSTR1 + n] = fmaxf(acc[r], 0.f);
    }
    __syncthreads();
    bf16x8 af2[2];
#pragma unroll
    for (int s = 0; s < 2; ++s) {
        f32x4 v0 = *(const f32x4*)(hw + mrow * HSTR1 + s * 32 + q * 8);
        f32x4 v1 = *(const f32x4*)(hw + mrow * HSTR1 + s * 32 + q * 8 + 4);
#pragma unroll
        for (int j = 0; j < 4; ++j) { af2[s][j] = f2bf(v0[j]); af2[s][j + 4] = f2bf(v1[j]); }
    }
#pragma unroll
    for (int nt = 0; nt < 4; ++nt) {
        int n = nt * 16 + mrow;
        float bias = b1b[n];
        f32x4 acc = {bias, bias, bias, bias};
#pragma unroll
        for (int s = 0; s < 2; ++s) {
            bf16x8 bfrag = *(const bf16x8*)(w1b_t + n * 64 + s * 32 + q * 8);
            acc = __builtin_amdgcn_mfma_f32_16x16x32_bf16(af2[s], bfrag, acc, 0, 0, 0);
        }
        if (act) {
#pragma unroll
            for (int r = 0; r < 4; ++r)
                h[(node0 + q * 4 + r) * HH + n] = fmaxf(acc[r], 0.f);
        }
    }
}

// ---------------------------------------------------------------------------
// Node MLP 2 + fused mean-pool accumulate
#define HSTR2 132
__global__ __launch_bounds__(256) void mlp2(
    const float* __restrict__ hin2,
    const short* __restrict__ w2a_t, const float* __restrict__ b2a,
    const short* __restrict__ w2b_t, const float* __restrict__ b2b,
    const int* __restrict__ batch, float* __restrict__ sums) {
    __shared__ float buf[4][16 * HSTR2];
    int lane = threadIdx.x & 63;
    int wv = threadIdx.x >> 6;
    int tile = blockIdx.x * 4 + wv;
    bool act = tile < (NN / 16);
    int tile_c = act ? tile : (NN / 16 - 1);
    int node0 = tile_c * 16;
    int mrow = lane & 15, q = lane >> 4;
    int m = node0 + mrow;
    float* bw = buf[wv];

    bf16x8 afrag[2];
#pragma unroll
    for (int s = 0; s < 2; ++s) {
        f32x4 h0 = *(const f32x4*)(hin2 + m * HH + s * 32 + q * 8);
        f32x4 h1 = *(const f32x4*)(hin2 + m * HH + s * 32 + q * 8 + 4);
#pragma unroll
        for (int j = 0; j < 4; ++j) {
            afrag[s][j] = f2bf(h0[j]);
            afrag[s][j + 4] = f2bf(h1[j]);
        }
    }
#pragma unroll
    for (int nt = 0; nt < 8; ++nt) {
        int n = nt * 16 + mrow;
        float bias = b2a[n];
        f32x4 acc = {bias, bias, bias, bias};
#pragma unroll
        for (int s = 0; s < 2; ++s) {
            bf16x8 bfrag = *(const bf16x8*)(w2a_t + n * HH + s * 32 + q * 8);
            acc = __builtin_amdgcn_mfma_f32_16x16x32_bf16(afrag[s], bfrag, acc, 0, 0, 0);
        }
#pragma unroll
        for (int r = 0; r < 4; ++r)
            bw[(q * 4 + r) * HSTR2 + n] = fmaxf(acc[r], 0.f);
    }
    __syncthreads();
    bf16x8 af2[4];
#pragma unroll
    for (int s = 0; s < 4; ++s) {
        f32x4 v0 = *(const f32x4*)(bw + mrow * HSTR2 + s * 32 + q * 8);
        f32x4 v1 = *(const f32x4*)(bw + mrow * HSTR2 + s * 32 + q * 8 + 4);
#pragma unroll
        for (int j = 0; j < 4; ++j) { af2[s][j] = f2bf(v0[j]); af2[s][j + 4] = f2bf(v1[j]); }
    }
    __syncthreads();
    f32x4 oacc[8];
#pragma unroll
    for (int nt = 0; nt < 8; ++nt) {
        int n = nt * 16 + mrow;
        float bias = b2b[n];
        f32x4 acc = {bias, bias, bias, bias};
#pragma unroll
        for (int s = 0; s < 4; ++s) {
            bf16x8 bfrag = *(const bf16x8*)(w2b_t + n * EMB + s * 32 + q * 8);
            acc = __builtin_amdgcn_mfma_f32_16x16x32_bf16(af2[s], bfrag, acc, 0, 0, 0);
        }
        oacc[nt] = acc;
    }
#pragma unroll
    for (int nt = 0; nt < 8; ++nt)
#pragma unroll
        for (int r = 0; r < 4; ++r)
            bw[(q * 4 + r) * HSTR2 + nt * 16 + mrow] = oacc[nt][r];
    __syncthreads();
    int bv = (act && lane < 16) ? batch[node0 + lane] : 0;
    if (act) {
#pragma unroll
        for (int cp = 0; cp < 2; ++cp) {
            int col = lane + cp * 64;
            float run = 0.f;
            int bprev = __shfl(bv, 0);
            for (int i = 0; i < 16; ++i) {
                int bg = __shfl(bv, i);
                if (bg != bprev) {
                    atomicAdd(&sums[bprev * EMB + col], run);
                    run = 0.f; bprev = bg;
                }
                run += bw[i * HSTR2 + col];
            }
            atomicAdd(&sums[bprev * EMB + col], run);
        }
    }
}

// ---------------------------------------------------------------------------
__global__ __launch_bounds__(128) void finalize(
    const float* __restrict__ sums, const int* __restrict__ batch,
    float* __restrict__ out) {
    int g = blockIdx.x;
    __shared__ int cnt_s;
    if (threadIdx.x == 0) {
        int lo = 0, hi = NN;
        while (lo < hi) { int mid = (lo + hi) >> 1; if (batch[mid] < g) lo = mid + 1; else hi = mid; }
        int lo2 = lo, hi2 = NN;
        while (lo2 < hi2) { int mid = (lo2 + hi2) >> 1; if (batch[mid] < g + 1) lo2 = mid + 1; else hi2 = mid; }
        cnt_s = lo2 - lo;
    }
    __syncthreads();
    int c = cnt_s > 1 ? cnt_s : 1;
    out[g * EMB + threadIdx.x] = sums[g * EMB + threadIdx.x] / (float)c;
}

// ---------------------------------------------------------------------------
extern "C" void kernel_launch(void* const* d_in, const int* in_sizes, int n_in,
                              void* d_out, int out_size, void* d_ws, size_t ws_size,
                              hipStream_t stream) {
    const float* x    = (const float*)d_in[0];
    const float* ea   = (const float*)d_in[1];
    const int*   ei   = (const int*)d_in[2];
    const int*   batch= (const int*)d_in[3];
    const float* el1w = (const float*)d_in[4];
    const float* el1b = (const float*)d_in[5];
    const float* w1a  = (const float*)d_in[6];
    const float* b1a  = (const float*)d_in[7];
    const float* w1b  = (const float*)d_in[8];
    const float* b1b  = (const float*)d_in[9];
    const float* el2w = (const float*)d_in[10];
    const float* el2b = (const float*)d_in[11];
    const float* w2a  = (const float*)d_in[12];
    const float* b2a  = (const float*)d_in[13];
    const float* w2b  = (const float*)d_in[14];
    const float* b2b  = (const float*)d_in[15];

    char* ws = (char*)d_ws;
    float* xin   = (float*)ws;                                  // [N][44] then reused as hin2 [N][64]
    float* hin2  = (float*)ws;
    float* hbuf  = (float*)(ws + 128000000);                    // [N][64] f32
    int2*  csr   = (int2*)(ws + 256000000);                     // [E] (src, eid)
    int*   rowptr= (int*)(ws + 272000000);                      // N+1
    int*   cursor= (int*)(ws + 274000064);                      // N
    int*   deg   = (int*)(ws + 276000064);                      // N
    int*   bsum  = (int*)(ws + 278000064);                      // NBLK
    int*   boff  = (int*)(ws + 278000576);                      // NBLK
    float* sums  = (float*)(ws + 278001088);                    // G*128 f32
    short* wts   = (short*)(ws + 286389696);                    // 32768 shorts
    short* w1a_t = wts;
    short* w1b_t = wts + 4096;
    short* w2a_t = wts + 8192;
    short* w2b_t = wts + 16384;

    hipMemsetAsync(deg, 0, (size_t)NN * 4, stream);
    hipMemsetAsync(sums, 0, (size_t)GG * EMB * 4, stream);

    prep_weights<<<128, 256, 0, stream>>>(w1a, w1b, w2a, w2b, wts);
    // CSR build
    hist_kernel<<<(EE + 255) / 256, 256, 0, stream>>>(ei, deg);
    scan_reduce<<<NBLK, 256, 0, stream>>>(deg, bsum);
    scan_mid<<<1, 128, 0, stream>>>(bsum, boff, rowptr);
    scan_final<<<NBLK, 256, 0, stream>>>(deg, boff, rowptr, cursor);
    scatter_kernel<<<(EE + 255) / 256, 256, 0, stream>>>(ei, cursor, csr);
    // Layer 1: 8 nodes/wave, 4 waves/block -> NN/32 blocks
    agg_gather<ND><<<NN / 32, 256, 0, stream>>>(x, ea, el1w, el1b, rowptr, csr, xin);
    mlp1<<<7813, 256, 0, stream>>>(xin, w1a_t, b1a, w1b_t, b1b, hbuf);
    // Layer 2
    agg_gather<HH><<<NN / 32, 256, 0, stream>>>(hbuf, ea, el2w, el2b, rowptr, csr, hin2);
    mlp2<<<7813, 256, 0, stream>>>(hin2, w2a_t, b2a, w2b_t, b2b, batch, sums);
    finalize<<<GG, 128, 0, stream>>>(sums, batch, (float*)d_out);
}

// Round 5
// 1246.911 us; speedup vs baseline: 1.1780x; 1.1523x over previous
//
#include <hip/hip_runtime.h>
#include <hip/hip_bf16.h>

#define NN 500000
#define EE 2000000
#define GG 16384
#define ND 44
#define ED 12
#define HH 64
#define EMB 128
#define NBLK 123          // ceil(NN / 4096) scan blocks

typedef __attribute__((ext_vector_type(8))) short bf16x8;
typedef __attribute__((ext_vector_type(4))) float f32x4;

// fp32 -> bf16 round-to-nearest-even, bit pattern as short
__device__ inline short f2bf(float v) {
    unsigned int x = __builtin_bit_cast(unsigned int, v);
    x += 0x7FFFu + ((x >> 16) & 1u);
    return (short)(x >> 16);
}

// ---------------------------------------------------------------------------
// Weight prep: transpose to [n][k] layout, cast to bf16, zero-pad K of w1a to 64
__global__ __launch_bounds__(256) void prep_weights(
    const float* __restrict__ w1a, const float* __restrict__ w1b,
    const float* __restrict__ w2a, const float* __restrict__ w2b,
    short* __restrict__ o) {
    int t = blockIdx.x * 256 + threadIdx.x;
    if (t < 4096) {
        int n = t >> 6, k = t & 63;
        o[t] = f2bf(k < ND ? w1a[k * HH + n] : 0.f);
    } else if (t < 8192) {
        int u = t - 4096; int n = u >> 6, k = u & 63;
        o[t] = f2bf(w1b[k * HH + n]);
    } else if (t < 16384) {
        int u = t - 8192; int n = u >> 6, k = u & 63;
        o[t] = f2bf(w2a[k * EMB + n]);
    } else if (t < 32768) {
        int u = t - 16384; int n = u >> 7, k = u & 127;
        o[t] = f2bf(w2b[k * EMB + n]);
    }
}

// ---------------------------------------------------------------------------
// CSR build: histogram of dst, exclusive scan, scatter (src, eid) by dst.
__global__ __launch_bounds__(256) void hist_kernel(const int* __restrict__ ei,
                                                   int* __restrict__ deg) {
    int e = blockIdx.x * 256 + threadIdx.x;
    if (e < EE) atomicAdd(&deg[ei[EE + e]], 1);
}

__global__ __launch_bounds__(256) void scan_reduce(const int* __restrict__ deg,
                                                   int* __restrict__ bsum) {
    int b = blockIdx.x, t = threadIdx.x;
    int base = b * 4096;
    int s = 0;
    for (int i = t; i < 4096; i += 256) {
        int g = base + i;
        if (g < NN) s += deg[g];
    }
#pragma unroll
    for (int off = 32; off; off >>= 1) s += __shfl_xor(s, off);
    __shared__ int ws[4];
    if ((t & 63) == 0) ws[t >> 6] = s;
    __syncthreads();
    if (t == 0) bsum[b] = ws[0] + ws[1] + ws[2] + ws[3];
}

__global__ __launch_bounds__(128) void scan_mid(const int* __restrict__ bsum,
                                                int* __restrict__ boff,
                                                int* __restrict__ rowptr) {
    int t = threadIdx.x;
    int v = (t < NBLK) ? bsum[t] : 0;
    int x = v;
#pragma unroll
    for (int off = 1; off < 64; off <<= 1) {
        int y = __shfl_up(x, off);
        if ((t & 63) >= off) x += y;
    }
    __shared__ int wt[2];
    if ((t & 63) == 63) wt[t >> 6] = x;
    __syncthreads();
    int xx = x + ((t >= 64) ? wt[0] : 0);
    if (t < NBLK) boff[t] = xx - v;
    if (t == 127) rowptr[NN] = xx;
}

__global__ __launch_bounds__(256) void scan_final(const int* __restrict__ deg,
                                                  const int* __restrict__ boff,
                                                  int* __restrict__ rowptr,
                                                  int* __restrict__ cursor) {
    int b = blockIdx.x, t = threadIdx.x;
    int base = b * 4096 + t * 16;
    int loc[16];
    int s = 0;
#pragma unroll
    for (int j = 0; j < 16; ++j) {
        int g = base + j;
        loc[j] = (g < NN) ? deg[g] : 0;
        s += loc[j];
    }
    int xinc = s;
#pragma unroll
    for (int off = 1; off < 64; off <<= 1) {
        int y = __shfl_up(xinc, off);
        if ((t & 63) >= off) xinc += y;
    }
    __shared__ int wt[4];
    if ((t & 63) == 63) wt[t >> 6] = xinc;
    __syncthreads();
    int wv = t >> 6, woff = 0;
#pragma unroll
    for (int k = 0; k < 4; ++k)
        if (k < wv) woff += wt[k];
    int run = boff[b] + woff + (xinc - s);
#pragma unroll
    for (int j = 0; j < 16; ++j) {
        int g = base + j;
        if (g < NN) { rowptr[g] = run; cursor[g] = run; }
        run += loc[j];
    }
}

__global__ __launch_bounds__(256) void scatter_kernel(const int* __restrict__ ei,
                                                      int* __restrict__ cursor,
                                                      int2* __restrict__ csr) {
    int e = blockIdx.x * 256 + threadIdx.x;
    if (e < EE) {
        int dst = ei[EE + e];
        int pos = atomicAdd(&cursor[dst], 1);
        csr[pos] = make_int2(ei[e], e);
    }
}

// ---------------------------------------------------------------------------
// Gather aggregation, 8 nodes/wave. out[i] = sum_{e: dst=i} relu(xf[src]+ea@W+b)
// (skip connection +xf[i] is applied downstream in the MLP kernels).
// All register indices compile-time; all per-edge control wave-uniform scalar.
template <int D>
__global__ __launch_bounds__(256) void agg_gather(
    const float* __restrict__ xf, const float* __restrict__ ea,
    const float* __restrict__ ew, const float* __restrict__ eb,
    const int* __restrict__ rowptr, const int2* __restrict__ csr,
    float* __restrict__ out) {
    int lane = threadIdx.x & 63;
    int wv = threadIdx.x >> 6;
    int i0 = (blockIdx.x * 4 + wv) * 8;
    if (i0 >= NN) return;
    float w0, w1, w2, w3, w4, w5, w6, w7, w8, w9, w10, w11, breg;
    if (D == 64 || lane < D) {
        w0 = ew[0 * D + lane];  w1 = ew[1 * D + lane];  w2 = ew[2 * D + lane];
        w3 = ew[3 * D + lane];  w4 = ew[4 * D + lane];  w5 = ew[5 * D + lane];
        w6 = ew[6 * D + lane];  w7 = ew[7 * D + lane];  w8 = ew[8 * D + lane];
        w9 = ew[9 * D + lane];  w10 = ew[10 * D + lane]; w11 = ew[11 * D + lane];
        breg = eb[lane];
    } else {
        w0=w1=w2=w3=w4=w5=w6=w7=w8=w9=w10=w11=0.f; breg = 0.f;
    }
    int rp = (lane <= 8) ? rowptr[i0 + lane] : 0;
    int beg = __builtin_amdgcn_readfirstlane(__builtin_amdgcn_readlane(rp, 0));
    int end = __builtin_amdgcn_readfirstlane(__builtin_amdgcn_readlane(rp, 8));
    // one-shot coalesced preload of this wave's CSR span (first 64 entries)
    int2 sel = make_int2(0, 0);
    if (beg + lane < end) sel = csr[beg + lane];
    int sel_x = sel.x, sel_y = sel.y;

    float acc = 0.f;
    int np = 0;
    int nb = __builtin_amdgcn_readlane(rp, 1);
    // FIX (r4 bug): flush leading empty nodes (boundary == beg). Without this,
    // a wave whose first node has zero in-edges never matches p1==nb and all
    // 8 node rows got zeroed by the tail loop.
    while (np < 8 && nb == beg) {
        if (D == 64 || lane < D) out[(size_t)(i0 + np) * D + lane] = 0.f;
        ++np;
        nb = (np < 8) ? __builtin_amdgcn_readlane(rp, np + 1) : 0x7fffffff;
    }

    auto LOADE = [&](int pos, float4& E0, float4& E1, float4& E2, float& XV) {
        if (pos < end) {
            int off = pos - beg;
            int src, eid;
            if (off < 64) {
                src = __builtin_amdgcn_readlane(sel_x, off);
                eid = __builtin_amdgcn_readlane(sel_y, off);
            } else {
                int2 se = csr[pos];
                src = __builtin_amdgcn_readfirstlane(se.x);
                eid = __builtin_amdgcn_readfirstlane(se.y);
            }
            const float4* ep = (const float4*)(ea + (size_t)eid * ED);
            E0 = ep[0]; E1 = ep[1]; E2 = ep[2];
            if (D == 64) XV = xf[(size_t)src * D + lane];
            else         XV = (lane < D) ? xf[(size_t)src * D + lane] : 0.f;
        }
    };
    auto CONSUME = [&](int pos, const float4& E0, const float4& E1,
                       const float4& E2, float XV) {
        if (pos < end) {
            float elin = breg;
            elin = fmaf(E0.x, w0, elin);  elin = fmaf(E0.y, w1, elin);
            elin = fmaf(E0.z, w2, elin);  elin = fmaf(E0.w, w3, elin);
            elin = fmaf(E1.x, w4, elin);  elin = fmaf(E1.y, w5, elin);
            elin = fmaf(E1.z, w6, elin);  elin = fmaf(E1.w, w7, elin);
            elin = fmaf(E2.x, w8, elin);  elin = fmaf(E2.y, w9, elin);
            elin = fmaf(E2.z, w10, elin); elin = fmaf(E2.w, w11, elin);
            acc += fmaxf(XV + elin, 0.f);
            int p1 = pos + 1;
            if (p1 == nb) {
                do {
                    if (D == 64 || lane < D) out[(size_t)(i0 + np) * D + lane] = acc;
                    acc = 0.f; ++np;
                    nb = (np < 8) ? __builtin_amdgcn_readlane(rp, np + 1) : 0x7fffffff;
                } while (p1 == nb);
            }
        }
    };

    float4 A0, A1, A2, B0, B1, B2, C0, C1, C2, D0, D1, D2;
    float Ax = 0.f, Bx = 0.f, Cx = 0.f, Dx = 0.f;
    int base = beg;
    LOADE(base + 0, A0, A1, A2, Ax);
    LOADE(base + 1, B0, B1, B2, Bx);
    LOADE(base + 2, C0, C1, C2, Cx);
    LOADE(base + 3, D0, D1, D2, Dx);
    while (base < end) {
        CONSUME(base + 0, A0, A1, A2, Ax);
        CONSUME(base + 1, B0, B1, B2, Bx);
        LOADE(base + 4, A0, A1, A2, Ax);
        LOADE(base + 5, B0, B1, B2, Bx);
        if (base + 2 >= end) break;
        CONSUME(base + 2, C0, C1, C2, Cx);
        CONSUME(base + 3, D0, D1, D2, Dx);
        LOADE(base + 6, C0, C1, C2, Cx);
        LOADE(base + 7, D0, D1, D2, Dx);
        base += 4;
    }
}

// ---------------------------------------------------------------------------
// Node MLP 1: h = relu( relu((x+agg) @ w1a + b1a) @ w1b + b1b )
#define HSTR1 68
__global__ __launch_bounds__(256) void mlp1(
    const float* __restrict__ xin, const float* __restrict__ x,
    const short* __restrict__ w1a_t, const float* __restrict__ b1a,
    const short* __restrict__ w1b_t, const float* __restrict__ b1b,
    float* __restrict__ h) {
    __shared__ float hid[4][16 * HSTR1];
    int lane = threadIdx.x & 63;
    int wv = threadIdx.x >> 6;
    int tile = blockIdx.x * 4 + wv;
    bool act = tile < (NN / 16);
    int tile_c = act ? tile : (NN / 16 - 1);
    int node0 = tile_c * 16;
    int mrow = lane & 15, q = lane >> 4;
    int m = node0 + mrow;
    float* hw = hid[wv];

    bf16x8 afrag[2];
    {
        f32x4 v0 = *(const f32x4*)(xin + m * ND + q * 8);
        f32x4 v1 = *(const f32x4*)(xin + m * ND + q * 8 + 4);
        f32x4 u0 = *(const f32x4*)(x + m * ND + q * 8);
        f32x4 u1 = *(const f32x4*)(x + m * ND + q * 8 + 4);
#pragma unroll
        for (int j = 0; j < 4; ++j) {
            afrag[0][j] = f2bf(v0[j] + u0[j]);
            afrag[0][j + 4] = f2bf(v1[j] + u1[j]);
        }
    }
#pragma unroll
    for (int j = 0; j < 8; ++j) {
        int k = 32 + q * 8 + j;
        afrag[1][j] = f2bf(k < ND ? xin[m * ND + k] + x[m * ND + k] : 0.f);
    }
#pragma unroll
    for (int nt = 0; nt < 4; ++nt) {
        int n = nt * 16 + mrow;
        float bias = b1a[n];
        f32x4 acc = {bias, bias, bias, bias};
#pragma unroll
        for (int s = 0; s < 2; ++s) {
            bf16x8 bfrag = *(const bf16x8*)(w1a_t + n * 64 + s * 32 + q * 8);
            acc = __builtin_amdgcn_mfma_f32_16x16x32_bf16(afrag[s], bfrag, acc, 0, 0, 0);
        }
#pragma unroll
        for (int r = 0; r < 4; ++r)
            hw[(q * 4 + r) * HSTR1 + n] = fmaxf(acc[r], 0.f);
    }
    __syncthreads();
    bf16x8 af2[2];
#pragma unroll
    for (int s = 0; s < 2; ++s) {
        f32x4 v0 = *(const f32x4*)(hw + mrow * HSTR1 + s * 32 + q * 8);
        f32x4 v1 = *(const f32x4*)(hw + mrow * HSTR1 + s * 32 + q * 8 + 4);
#pragma unroll
        for (int j = 0; j < 4; ++j) { af2[s][j] = f2bf(v0[j]); af2[s][j + 4] = f2bf(v1[j]); }
    }
#pragma unroll
    for (int nt = 0; nt < 4; ++nt) {
        int n = nt * 16 + mrow;
        float bias = b1b[n];
        f32x4 acc = {bias, bias, bias, bias};
#pragma unroll
        for (int s = 0; s < 2; ++s) {
            bf16x8 bfrag = *(const bf16x8*)(w1b_t + n * 64 + s * 32 + q * 8);
            acc = __builtin_amdgcn_mfma_f32_16x16x32_bf16(af2[s], bfrag, acc, 0, 0, 0);
        }
        if (act) {
#pragma unroll
            for (int r = 0; r < 4; ++r)
                h[(node0 + q * 4 + r) * HH + n] = fmaxf(acc[r], 0.f);
        }
    }
}

// ---------------------------------------------------------------------------
// Node MLP 2 + fused mean-pool accumulate: in = h + agg2
#define HSTR2 132
__global__ __launch_bounds__(256) void mlp2(
    const float* __restrict__ hin2, const float* __restrict__ hbuf,
    const short* __restrict__ w2a_t, const float* __restrict__ b2a,
    const short* __restrict__ w2b_t, const float* __restrict__ b2b,
    const int* __restrict__ batch, float* __restrict__ sums) {
    __shared__ float buf[4][16 * HSTR2];
    int lane = threadIdx.x & 63;
    int wv = threadIdx.x >> 6;
    int tile = blockIdx.x * 4 + wv;
    bool act = tile < (NN / 16);
    int tile_c = act ? tile : (NN / 16 - 1);
    int node0 = tile_c * 16;
    int mrow = lane & 15, q = lane >> 4;
    int m = node0 + mrow;
    float* bw = buf[wv];

    bf16x8 afrag[2];
#pragma unroll
    for (int s = 0; s < 2; ++s) {
        f32x4 h0 = *(const f32x4*)(hin2 + m * HH + s * 32 + q * 8);
        f32x4 h1 = *(const f32x4*)(hin2 + m * HH + s * 32 + q * 8 + 4);
        f32x4 a0 = *(const f32x4*)(hbuf + m * HH + s * 32 + q * 8);
        f32x4 a1 = *(const f32x4*)(hbuf + m * HH + s * 32 + q * 8 + 4);
#pragma unroll
        for (int j = 0; j < 4; ++j) {
            afrag[s][j] = f2bf(h0[j] + a0[j]);
            afrag[s][j + 4] = f2bf(h1[j] + a1[j]);
        }
    }
#pragma unroll
    for (int nt = 0; nt < 8; ++nt) {
        int n = nt * 16 + mrow;
        float bias = b2a[n];
        f32x4 acc = {bias, bias, bias, bias};
#pragma unroll
        for (int s = 0; s < 2; ++s) {
            bf16x8 bfrag = *(const bf16x8*)(w2a_t + n * HH + s * 32 + q * 8);
            acc = __builtin_amdgcn_mfma_f32_16x16x32_bf16(afrag[s], bfrag, acc, 0, 0, 0);
        }
#pragma unroll
        for (int r = 0; r < 4; ++r)
            bw[(q * 4 + r) * HSTR2 + n] = fmaxf(acc[r], 0.f);
    }
    __syncthreads();
    bf16x8 af2[4];
#pragma unroll
    for (int s = 0; s < 4; ++s) {
        f32x4 v0 = *(const f32x4*)(bw + mrow * HSTR2 + s * 32 + q * 8);
        f32x4 v1 = *(const f32x4*)(bw + mrow * HSTR2 + s * 32 + q * 8 + 4);
#pragma unroll
        for (int j = 0; j < 4; ++j) { af2[s][j] = f2bf(v0[j]); af2[s][j + 4] = f2bf(v1[j]); }
    }
    __syncthreads();
    f32x4 oacc[8];
#pragma unroll
    for (int nt = 0; nt < 8; ++nt) {
        int n = nt * 16 + mrow;
        float bias = b2b[n];
        f32x4 acc = {bias, bias, bias, bias};
#pragma unroll
        for (int s = 0; s < 4; ++s) {
            bf16x8 bfrag = *(const bf16x8*)(w2b_t + n * EMB + s * 32 + q * 8);
            acc = __builtin_amdgcn_mfma_f32_16x16x32_bf16(af2[s], bfrag, acc, 0, 0, 0);
        }
        oacc[nt] = acc;
    }
#pragma unroll
    for (int nt = 0; nt < 8; ++nt)
#pragma unroll
        for (int r = 0; r < 4; ++r)
            bw[(q * 4 + r) * HSTR2 + nt * 16 + mrow] = oacc[nt][r];
    __syncthreads();
    int bv = (act && lane < 16) ? batch[node0 + lane] : 0;
    if (act) {
#pragma unroll
        for (int cp = 0; cp < 2; ++cp) {
            int col = lane + cp * 64;
            float run = 0.f;
            int bprev = __shfl(bv, 0);
            for (int i = 0; i < 16; ++i) {
                int bg = __shfl(bv, i);
                if (bg != bprev) {
                    atomicAdd(&sums[bprev * EMB + col], run);
                    run = 0.f; bprev = bg;
                }
                run += bw[i * HSTR2 + col];
            }
            atomicAdd(&sums[bprev * EMB + col], run);
        }
    }
}

// ---------------------------------------------------------------------------
__global__ __launch_bounds__(128) void finalize(
    const float* __restrict__ sums, const int* __restrict__ batch,
    float* __restrict__ out) {
    int g = blockIdx.x;
    __shared__ int cnt_s;
    if (threadIdx.x == 0) {
        int lo = 0, hi = NN;
        while (lo < hi) { int mid = (lo + hi) >> 1; if (batch[mid] < g) lo = mid + 1; else hi = mid; }
        int lo2 = lo, hi2 = NN;
        while (lo2 < hi2) { int mid = (lo2 + hi2) >> 1; if (batch[mid] < g + 1) lo2 = mid + 1; else hi2 = mid; }
        cnt_s = lo2 - lo;
    }
    __syncthreads();
    int c = cnt_s > 1 ? cnt_s : 1;
    out[g * EMB + threadIdx.x] = sums[g * EMB + threadIdx.x] / (float)c;
}

// ---------------------------------------------------------------------------
extern "C" void kernel_launch(void* const* d_in, const int* in_sizes, int n_in,
                              void* d_out, int out_size, void* d_ws, size_t ws_size,
                              hipStream_t stream) {
    const float* x    = (const float*)d_in[0];
    const float* ea   = (const float*)d_in[1];
    const int*   ei   = (const int*)d_in[2];
    const int*   batch= (const int*)d_in[3];
    const float* el1w = (const float*)d_in[4];
    const float* el1b = (const float*)d_in[5];
    const float* w1a  = (const float*)d_in[6];
    const float* b1a  = (const float*)d_in[7];
    const float* w1b  = (const float*)d_in[8];
    const float* b1b  = (const float*)d_in[9];
    const float* el2w = (const float*)d_in[10];
    const float* el2b = (const float*)d_in[11];
    const float* w2a  = (const float*)d_in[12];
    const float* b2a  = (const float*)d_in[13];
    const float* w2b  = (const float*)d_in[14];
    const float* b2b  = (const float*)d_in[15];

    char* ws = (char*)d_ws;
    float* xin   = (float*)ws;                                  // [N][44] agg1 out, reused as hin2 [N][64]
    float* hin2  = (float*)ws;
    float* hbuf  = (float*)(ws + 128000000);                    // [N][64] f32
    int2*  csr   = (int2*)(ws + 256000000);                     // [E] (src, eid)
    int*   rowptr= (int*)(ws + 272000000);                      // N+1
    int*   cursor= (int*)(ws + 274000064);                      // N
    int*   deg   = (int*)(ws + 276000064);                      // N
    int*   bsum  = (int*)(ws + 278000064);                      // NBLK
    int*   boff  = (int*)(ws + 278000576);                      // NBLK
    float* sums  = (float*)(ws + 278001088);                    // G*128 f32
    short* wts   = (short*)(ws + 286389696);                    // 32768 shorts
    short* w1a_t = wts;
    short* w1b_t = wts + 4096;
    short* w2a_t = wts + 8192;
    short* w2b_t = wts + 16384;

    hipMemsetAsync(deg, 0, (size_t)NN * 4, stream);
    hipMemsetAsync(sums, 0, (size_t)GG * EMB * 4, stream);

    prep_weights<<<128, 256, 0, stream>>>(w1a, w1b, w2a, w2b, wts);
    // CSR build
    hist_kernel<<<(EE + 255) / 256, 256, 0, stream>>>(ei, deg);
    scan_reduce<<<NBLK, 256, 0, stream>>>(deg, bsum);
    scan_mid<<<1, 128, 0, stream>>>(bsum, boff, rowptr);
    scan_final<<<NBLK, 256, 0, stream>>>(deg, boff, rowptr, cursor);
    scatter_kernel<<<(EE + 255) / 256, 256, 0, stream>>>(ei, cursor, csr);
    // Layer 1
    agg_gather<ND><<<NN / 32, 256, 0, stream>>>(x, ea, el1w, el1b, rowptr, csr, xin);
    mlp1<<<7813, 256, 0, stream>>>(xin, x, w1a_t, b1a, w1b_t, b1b, hbuf);
    // Layer 2
    agg_gather<HH><<<NN / 32, 256, 0, stream>>>(hbuf, ea, el2w, el2b, rowptr, csr, hin2);
    mlp2<<<7813, 256, 0, stream>>>(hin2, hbuf, w2a_t, b2a, w2b_t, b2b, batch, sums);
    finalize<<<GG, 128, 0, stream>>>(sums, batch, (float*)d_out);
}